// Round 1
// baseline (5105.721 us; speedup 1.0000x reference)
//
#include <hip/hip_runtime.h>
#include <math.h>

#define WSZ 8
#define SHIFT 4
#define HD 32
#define NH 6
#define CH 192
#define HP 256
#define WP 256
#define NWY 32
#define NWX 32
#define NPX 64
#define SCALE 0.17677669529663687f

// LDS row strides (chosen to avoid bank conflicts)
#define QS 33     // q/k/v row stride (fp32)
#define SS 65     // sim row stride
#define AOS 200   // attn-out row stride

__global__ __launch_bounds__(512)
void wmsa_fused(const float* __restrict__ x,
                const float* __restrict__ w_qkv,
                const float* __restrict__ b_qkv,
                const float* __restrict__ rel_pos,
                const float* __restrict__ w_out,
                const float* __restrict__ b_out,
                float* __restrict__ out)
{
    __shared__ float xw[NPX][CH];       // 49152 B
    __shared__ float qh[NPX][QS];       // 8448 B
    __shared__ float kh[NPX][QS];       // 8448 B
    __shared__ float vh[NPX][QS];       // 8448 B
    __shared__ float simb[NPX][SS];     // 16640 B
    __shared__ float attn[NPX][AOS];    // 51200 B
    // total 142336 B

    const int t   = threadIdx.x;
    const int blk = blockIdx.x;
    const int b   = blk >> 10;          // / 1024 windows per batch
    const int w   = blk & 1023;
    const int wy  = w >> 5;
    const int wx  = w & 31;

    // ---- load x window with forward roll applied ----
    // rolled[gy][gx] = x[(gy+SHIFT)%256][(gx+SHIFT)%256]
    // 64 rows x 48 float4 = 3072 float4 -> 6 per thread
    #pragma unroll
    for (int i = 0; i < 6; ++i) {
        int idx = t + i * 512;
        int p   = idx / 48;
        int c4  = idx % 48;
        int py = p >> 3, px = p & 7;
        int sy = (wy * WSZ + py + SHIFT) & 255;
        int sx = (wx * WSZ + px + SHIFT) & 255;
        const float4* src = (const float4*)(x + (((size_t)b * HP + sy) * WP + sx) * CH);
        float4 v4 = src[c4];
        xw[p][c4 * 4 + 0] = v4.x;
        xw[p][c4 * 4 + 1] = v4.y;
        xw[p][c4 * 4 + 2] = v4.z;
        xw[p][c4 * 4 + 3] = v4.w;
    }
    __syncthreads();

    const int tc = t & 31;   // 0..31 : head-dim column
    const int tp = t >> 5;   // 0..15 : pixel group (4 pixels each)
    const bool edgeY = (wy == NWY - 1);
    const bool edgeX = (wx == NWX - 1);

    for (int h = 0; h < NH; ++h) {
        // ---- QKV for head h: thread computes q/k/v[tc] for 4 pixels ----
        {
            const int jq = h * HD + tc;
            const int jk = CH + h * HD + tc;
            const int jv = 2 * CH + h * HD + tc;
            float accq[4], acck[4], accv[4];
            const float bq = b_qkv[jq], bk = b_qkv[jk], bv = b_qkv[jv];
            #pragma unroll
            for (int i = 0; i < 4; ++i) { accq[i] = bq; acck[i] = bk; accv[i] = bv; }
            #pragma unroll 4
            for (int c = 0; c < CH; ++c) {
                float wq = w_qkv[c * 576 + jq];
                float wk = w_qkv[c * 576 + jk];
                float wv = w_qkv[c * 576 + jv];
                #pragma unroll
                for (int i = 0; i < 4; ++i) {
                    float xv = xw[tp * 4 + i][c];
                    accq[i] += xv * wq;
                    acck[i] += xv * wk;
                    accv[i] += xv * wv;
                }
            }
            #pragma unroll
            for (int i = 0; i < 4; ++i) {
                qh[tp * 4 + i][tc] = accq[i];
                kh[tp * 4 + i][tc] = acck[i];
                vh[tp * 4 + i][tc] = accv[i];
            }
        }
        __syncthreads();

        // ---- sim + bias + mask + softmax (row p spread over 8 lanes) ----
        {
            const int p  = t >> 3;             // 0..63
            const int qb = (t & 7) * 8;        // 8 key columns per thread
            const int py = p >> 3, px = p & 7;
            float s[8];
            #pragma unroll
            for (int i = 0; i < 8; ++i) s[i] = 0.f;
            #pragma unroll 4
            for (int d = 0; d < HD; ++d) {
                float qv = qh[p][d];
                #pragma unroll
                for (int i = 0; i < 8; ++i) s[i] += qv * kh[qb + i][d];
            }
            #pragma unroll
            for (int i = 0; i < 8; ++i) {
                int q  = qb + i;
                int qy = q >> 3, qx = q & 7;
                float val = s[i] * SCALE + rel_pos[h * 225 + (py - qy + 7) * 15 + (px - qx + 7)];
                bool msk = (edgeY && ((py < SHIFT) != (qy < SHIFT))) ||
                           (edgeX && ((px < SHIFT) != (qx < SHIFT)));
                s[i] = msk ? -1e30f : val;
            }
            // softmax across the 8-lane group (xor masks 1,2,4 stay in group)
            float m = s[0];
            #pragma unroll
            for (int i = 1; i < 8; ++i) m = fmaxf(m, s[i]);
            #pragma unroll
            for (int off = 1; off < 8; off <<= 1) m = fmaxf(m, __shfl_xor(m, off));
            float sum = 0.f;
            #pragma unroll
            for (int i = 0; i < 8; ++i) { s[i] = __expf(s[i] - m); sum += s[i]; }
            #pragma unroll
            for (int off = 1; off < 8; off <<= 1) sum += __shfl_xor(sum, off);
            float inv = 1.f / sum;
            #pragma unroll
            for (int i = 0; i < 8; ++i) simb[p][qb + i] = s[i] * inv;
        }
        __syncthreads();

        // ---- PV: thread computes attn[p][h*32 + dg..dg+3] ----
        {
            const int p  = t >> 3;
            const int dg = (t & 7) * 4;
            float acc[4] = {0.f, 0.f, 0.f, 0.f};
            #pragma unroll 4
            for (int q = 0; q < NPX; ++q) {
                float pr = simb[p][q];
                #pragma unroll
                for (int j = 0; j < 4; ++j) acc[j] += pr * vh[q][dg + j];
            }
            #pragma unroll
            for (int j = 0; j < 4; ++j) attn[p][h * HD + dg + j] = acc[j];
        }
        __syncthreads();   // protects qh/kh/vh reuse next head; last iter protects attn for proj
    }

    // ---- output projection + inverse roll scatter ----
    {
        float acc[4][6];
        #pragma unroll
        for (int m = 0; m < 6; ++m) {
            float bb = b_out[tc + 32 * m];
            #pragma unroll
            for (int i = 0; i < 4; ++i) acc[i][m] = bb;
        }
        #pragma unroll 4
        for (int c = 0; c < CH; ++c) {
            float wv[6];
            #pragma unroll
            for (int m = 0; m < 6; ++m) wv[m] = w_out[c * CH + tc + 32 * m];
            #pragma unroll
            for (int i = 0; i < 4; ++i) {
                float av = attn[tp * 4 + i][c];
                #pragma unroll
                for (int m = 0; m < 6; ++m) acc[i][m] += av * wv[m];
            }
        }
        #pragma unroll
        for (int i = 0; i < 4; ++i) {
            int p  = tp * 4 + i;
            int py = p >> 3, px = p & 7;
            // inverse roll: pre-roll pixel (gy,gx) lands at ((gy+SHIFT)%256,(gx+SHIFT)%256)
            int sy = (wy * WSZ + py + SHIFT) & 255;
            int sx = (wx * WSZ + px + SHIFT) & 255;
            float* dst = out + (((size_t)b * HP + sy) * WP + sx) * CH;
            #pragma unroll
            for (int m = 0; m < 6; ++m) dst[tc + 32 * m] = acc[i][m];
        }
    }
}

extern "C" void kernel_launch(void* const* d_in, const int* in_sizes, int n_in,
                              void* d_out, int out_size, void* d_ws, size_t ws_size,
                              hipStream_t stream) {
    const float* x       = (const float*)d_in[0];
    const float* w_qkv   = (const float*)d_in[1];
    const float* b_qkv   = (const float*)d_in[2];
    const float* rel_pos = (const float*)d_in[3];
    const float* w_out   = (const float*)d_in[4];
    const float* b_out   = (const float*)d_in[5];
    wmsa_fused<<<dim3(8192), dim3(512), 0, stream>>>(
        x, w_qkv, b_qkv, rel_pos, w_out, b_out, (float*)d_out);
}